// Round 2
// baseline (8400.426 us; speedup 1.0000x reference)
//
#include <hip/hip_runtime.h>

// RecurrentGaussianActor: fused LSTM(64->256) + Linear+ReLU(256) + 2 heads(16).
// One WG per batch row (256 WGs x 1024 threads), persistent over T=1000 steps.
//
// Round-3 fixes over the (correct but spilled) quad-sliced round-2 version:
//  * amdgpu_waves_per_eu(4,4): LDS (157KB) already caps the CU at 1 block =
//    4 waves/SIMD, but the allocator targeted 8 waves/SIMD -> 64 VGPRs ->
//    wreg (96 regs) spilled to scratch -> 10 GB HBM FETCH, 7.5 ms. Pinning
//    min=max=4 gives the allocator the full 128-reg budget for free.
//  * Every phase restructured so peak live regs <= 128 with wreg live-through:
//    xg = one row (tid) per thread, one w-h8 in flight; layer2 = 256 threads
//    x 8 timesteps (w2 read ONCE per CU per chunk); heads unchanged.
//  * hbuf h-slices padded to 144B stride: slice k starts at bank 4k (was
//    bank 0 for all k -> 4-way conflict, 1.3e8 SQ_LDS_BANK_CONFLICT).
//  * wih/w2/wm transposed in prep -> lane-coalesced global reads, minimal L2.

#define NB 256
#define NT 1000
#define NF 64
#define NH 256
#define NG 1024
#define NA 16
#define NTHREADS 1024
#define CHUNK 8
#define NCHUNK (NT / CHUNK)
#define HSLICE 36  // h2 units per padded h-slice (64 f16 + 8 f16 pad = 144 B)

typedef _Float16 h2 __attribute__((ext_vector_type(2)));
typedef _Float16 h8 __attribute__((ext_vector_type(8)));
typedef float f4 __attribute__((ext_vector_type(4)));

__device__ __forceinline__ float fdot2(h2 a, h2 b, float c) {
  return __builtin_amdgcn_fdot2(a, b, c, false);
}
__device__ __forceinline__ float fexp2(float x) { return __builtin_amdgcn_exp2f(x); }
__device__ __forceinline__ float frcp(float x) { return __builtin_amdgcn_rcpf(x); }
__device__ __forceinline__ float sigmoidf_(float x) {
  return frcp(1.f + fexp2(-1.4426950408889634f * x));
}
__device__ __forceinline__ float tanhfast(float x) {
  float a = fabsf(x);
  float e = fexp2(-2.8853900817779268f * a);
  float r = (1.f - e) * frcp(1.f + e);
  return __builtin_copysignf(r, x);
}
// dot of 8 f16 elements held in two h8 vectors (4 chained v_dot2_f32_f16)
__device__ __forceinline__ float dot8(h8 x, h8 w, float acc) {
  acc = fdot2(__builtin_shufflevector(x, x, 0, 1), __builtin_shufflevector(w, w, 0, 1), acc);
  acc = fdot2(__builtin_shufflevector(x, x, 2, 3), __builtin_shufflevector(w, w, 2, 3), acc);
  acc = fdot2(__builtin_shufflevector(x, x, 4, 5), __builtin_shufflevector(w, w, 4, 5), acc);
  acc = fdot2(__builtin_shufflevector(x, x, 6, 7), __builtin_shufflevector(w, w, 6, 7), acc);
  return acc;
}
// quad_perm DPP: CTRL=0xB1 -> lanes (1,0,3,2) [xor1]; 0x4E -> (2,3,0,1) [xor2]
template <int CTRL>
__device__ __forceinline__ float qperm(float x) {
  return __int_as_float(
      __builtin_amdgcn_update_dpp(0, __float_as_int(x), CTRL, 0xF, 0xF, true));
}

// ---- prep: convert/pack weights to f16 in workspace (~790 KB) ----
// whh  : [row][128 pairs]            (as before; feeds LDS part + wreg part)
// wih_t: [j=h8-chunk 0..8)][row]     transposed -> coalesced xg reads
// w2t  : [c=h8-chunk 0..32)][o]      transposed -> coalesced layer2 reads
// wmt  : [c=h8-chunk 0..32)][j 0..32) transposed -> coalesced head reads
__global__ void prep_kernel(const float* __restrict__ Wih, const float* __restrict__ Whh,
                            const float* __restrict__ bih, const float* __restrict__ bhh,
                            const float* __restrict__ W2, const float* __restrict__ Wm,
                            const float* __restrict__ Ws,
                            h2* __restrict__ whh, h2* __restrict__ wih_t,
                            h2* __restrict__ w2t, h2* __restrict__ wmt,
                            float* __restrict__ bg) {
  int i = blockIdx.x * 256 + threadIdx.x;
  if (i < 1024 * 128) {  // W_hh [1024][256] -> [1024][128] pairs
    int j = i >> 7, p = i & 127;
    whh[i] = h2{(_Float16)Whh[j * 256 + 2 * p], (_Float16)Whh[j * 256 + 2 * p + 1]};
  }
  if (i < 1024 * 32) {   // W_ih row r, pair p -> wih_t[(p>>2)*4096 + r*4 + (p&3)]
    int r = i >> 5, p = i & 31;
    wih_t[(p >> 2) * 4096 + r * 4 + (p & 3)] =
        h2{(_Float16)Wih[r * 64 + 2 * p], (_Float16)Wih[r * 64 + 2 * p + 1]};
  }
  if (i < 256 * 128) {   // W2 row o, pair p -> w2t[(p>>2)*1024 + o*4 + (p&3)]
    int o = i >> 7, p = i & 127;
    w2t[(p >> 2) * 1024 + o * 4 + (p & 3)] =
        h2{(_Float16)W2[o * 256 + 2 * p], (_Float16)W2[o * 256 + 2 * p + 1]};
  }
  if (i < 32 * 128) {    // Wm rows 0..15, Ws rows 16..31 -> wmt[(p>>2)*128 + j*4 + (p&3)]
    int j = i >> 7, p = i & 127;
    float v0, v1;
    if (j < 16) { v0 = Wm[j * 256 + 2 * p]; v1 = Wm[j * 256 + 2 * p + 1]; }
    else        { v0 = Ws[(j - 16) * 256 + 2 * p]; v1 = Ws[(j - 16) * 256 + 2 * p + 1]; }
    wmt[(p >> 2) * 128 + j * 4 + (p & 3)] = h2{(_Float16)v0, (_Float16)v1};
  }
  if (i < 1024) bg[i] = bih[i] + bhh[i];
}

// ---- main fused persistent kernel: 1 WG per batch row ----
__global__ __launch_bounds__(NTHREADS)
__attribute__((amdgpu_waves_per_eu(4, 4))) void actor_kernel(
    const float* __restrict__ obs,
    const h2* __restrict__ whh, const h2* __restrict__ wih_t,
    const h2* __restrict__ w2t, const h2* __restrict__ wmt,
    const float* __restrict__ bg, const float* __restrict__ b2,
    const float* __restrict__ bm, const float* __restrict__ bs,
    float* __restrict__ out) {
  // W_hh h8-slices 0..1 of each thread's 4 rows: [g*2+s][tid], lane-linear b128
  __shared__ __align__(16) h8 whh_l[8 * 1024];             // 131072 B
  __shared__ __align__(16) _Float16 xg_l[CHUNK * NG];      // 16384 B
  __shared__ __align__(16) h2 hbuf[2][4 * HSLICE];         // 1152 B padded dbuf h
  __shared__ __align__(16) h2 hch[CHUNK * NH / 2];         // 4096 B  h history
  __shared__ __align__(16) h2 xbuf[CHUNK * NF / 2];        // 1024 B  obs chunk
  __shared__ __align__(16) h2 x2b[CHUNK * NH / 2];         // 4096 B  layer2 out
  // total 157824 B <= 163840

  const int tid = threadIdx.x;
  const int b = blockIdx.x;
  const int u = tid >> 2;     // hidden unit owned by this quad
  const int k = tid & 3;      // gate slot / h-slice index
  const int R = k * 256 + u;  // this lane's gate row in the step loop

  // ---- register-resident W_hh: h8 slices 2..7 of rows {g*256+u}, slice k ----
  // 24 x h8 = 96 VGPRs. VOLATILE: no remat-from-global inside the step loop.
  h8 wreg[24];
  {
    const volatile h8* vw = (const volatile h8*)whh;  // row stride = 32 h8
#pragma unroll
    for (int g = 0; g < 4; g++)
#pragma unroll
      for (int j = 0; j < 6; j++)
        wreg[g * 6 + j] = vw[(g * 256 + u) * 32 + k * 8 + 2 + j];
  }
  // ---- LDS-resident W_hh: h8 slices 0..1 per row, layout [g*2+s][tid] ----
  {
    const h8* whh8 = (const h8*)whh;
#pragma unroll
    for (int g = 0; g < 4; g++)
#pragma unroll
      for (int s = 0; s < 2; s++)
        whh_l[(g * 2 + s) * 1024 + tid] = whh8[(g * 256 + u) * 32 + k * 8 + s];
  }
  if (tid < 4 * HSLICE) hbuf[0][tid] = h2{(_Float16)0.f, (_Float16)0.f};
  float c_state = 0.f;  // replicated across the 4 lanes of a quad
  const float bgv = bg[tid];        // xg bias for row tid
  const float b2v = b2[tid & 255];
  const int oh = tid & 31;
  const float hbv = (oh < NA) ? bm[oh] : bs[oh - NA];
  __syncthreads();

  const float* obs_b = obs + (size_t)b * NT * NF;
  float* out_means = out;
  float* out_stds = out + (size_t)NB * NT * NA;

  for (int ch = 0; ch < NCHUNK; ++ch) {
    const int t0 = ch * CHUNK;

    // ---- stage obs chunk -> f16 pairs in LDS ----
    if (tid < 128) {
      int t = tid >> 4, fq = tid & 15;
      f4 v = *(const f4*)(obs_b + (size_t)(t0 + t) * NF + fq * 4);
      xbuf[t * 32 + fq * 2] = h2{(_Float16)v[0], (_Float16)v[1]};
      xbuf[t * 32 + fq * 2 + 1] = h2{(_Float16)v[2], (_Float16)v[3]};
    }
    __syncthreads();

    // ---- xg[t][tid] = obs[t] . W_ih[tid] + bias; one w-h8 in flight ----
    {
      float acc[CHUNK];
#pragma unroll
      for (int t = 0; t < CHUNK; t++) acc[t] = bgv;
      const h8* wt = (const h8*)wih_t;  // [j][row], coalesced across lanes
      for (int j = 0; j < 8; j++) {
        h8 w = wt[j * 1024 + tid];
#pragma unroll
        for (int t = 0; t < CHUNK; t++) {
          h8 xv = *(const h8*)&xbuf[t * 32 + j * 4];
          acc[t] = dot8(xv, w, acc[t]);
        }
      }
#pragma unroll
      for (int t = 0; t < CHUNK; t++) xg_l[t * NG + tid] = (_Float16)acc[t];
    }
    __syncthreads();  // xg read cross-thread (row R != tid)

    // ---- 8 recurrent LSTM steps, ONE barrier each ----
    for (int t = 0; t < CHUNK; t++) {
      // padded slice: k*144B -> starting bank 4k -> the 4 quad addresses are
      // on disjoint banks (was all-bank-0: 4-way conflict).
      const _Float16* hb = (const _Float16*)&hbuf[t & 1][k * HSLICE];
      float xgv = (float)xg_l[t * NG + R];
      float p0 = (k == 0) ? xgv : 0.f;
      float p1 = (k == 1) ? xgv : 0.f;
      float p2 = (k == 2) ? xgv : 0.f;
      float p3 = (k == 3) ? xgv : 0.f;
#pragma unroll
      for (int s = 0; s < 2; s++) {
        h8 hv = *(const h8*)(hb + s * 8);
        p0 = dot8(hv, whh_l[(0 + s) * 1024 + tid], p0);
        p1 = dot8(hv, whh_l[(2 + s) * 1024 + tid], p1);
        p2 = dot8(hv, whh_l[(4 + s) * 1024 + tid], p2);
        p3 = dot8(hv, whh_l[(6 + s) * 1024 + tid], p3);
      }
#pragma unroll
      for (int j = 0; j < 6; j++) {
        h8 hv = *(const h8*)(hb + 16 + j * 8);
        p0 = dot8(hv, wreg[j], p0);
        p1 = dot8(hv, wreg[6 + j], p1);
        p2 = dot8(hv, wreg[12 + j], p2);
        p3 = dot8(hv, wreg[18 + j], p3);
      }
      // quad butterfly reduce (DPP, VALU-only): all 4 lanes end with all 4
      // full gate pre-activations -> replicated gate math, identical c_state.
      p0 += qperm<0xB1>(p0);
      p1 += qperm<0xB1>(p1);
      p2 += qperm<0xB1>(p2);
      p3 += qperm<0xB1>(p3);
      p0 += qperm<0x4E>(p0);
      p1 += qperm<0x4E>(p1);
      p2 += qperm<0x4E>(p2);
      p3 += qperm<0x4E>(p3);
      float gi = sigmoidf_(p0);
      float gf = sigmoidf_(p1);
      float gg = tanhfast(p2);
      float go = sigmoidf_(p3);
      c_state = gf * c_state + gi * gg;
      float hval = go * tanhfast(c_state);
      if (k == 0) {
        _Float16 hh = (_Float16)hval;
        // publish h(t+1) into the padded slice layout of the other buffer
        ((_Float16*)&hbuf[(t + 1) & 1][(u >> 6) * HSLICE])[u & 63] = hh;
        ((_Float16*)hch)[t * NH + u] = hh;  // history for layer2
      }
      __syncthreads();  // h(t+1) visible; hbuf[t&1] free for step t+2's write
    }

    // ---- layer2: x2 = relu(h @ W2^T + b2); 256 threads x 8 timesteps ----
    // w2t read exactly once per CU per chunk (128 KB), coalesced; hch reads
    // are full-wave broadcasts (address independent of lane).
    if (tid < 256) {
      const int o = tid;
      float acc[CHUNK];
#pragma unroll
      for (int t = 0; t < CHUNK; t++) acc[t] = b2v;
      const h8* wt2 = (const h8*)w2t;
      for (int c = 0; c < 32; c++) {
        h8 w = wt2[c * 256 + o];
#pragma unroll
        for (int t = 0; t < CHUNK; t++) {
          h8 xv = *(const h8*)&hch[t * 128 + c * 4];
          acc[t] = dot8(xv, w, acc[t]);
        }
      }
#pragma unroll
      for (int t = 0; t < CHUNK; t++)
        ((_Float16*)x2b)[t * NH + o] = (_Float16)fmaxf(acc[t], 0.f);
    }
    __syncthreads();

    // ---- heads: 32 outputs x 8 timesteps on first 256 threads ----
    if (tid < 256) {
      const int tt = tid >> 5;
      const h8* wm8 = (const h8*)wmt;  // [c][oh], coalesced across lanes
      float acc = 0.f;
#pragma unroll 2
      for (int c = 0; c < 32; c++) {
        h8 xv = *(const h8*)&x2b[tt * 128 + c * 4];
        acc = dot8(xv, wm8[c * 32 + oh], acc);
      }
      acc += hbv;
      const size_t idx = ((size_t)b * NT + (t0 + tt)) * NA + (oh & 15);
      if (oh < NA) {
        out_means[idx] = acc;
      } else {
        float ls = fminf(fmaxf(acc, -20.f), 2.f);
        out_stds[idx] = fexp2(1.4426950408889634f * ls);
      }
    }
    // no trailing barrier: next chunk's first write to x2b (its layer2) is
    // separated from these reads by the staging/xg/step barriers.
  }
}

extern "C" void kernel_launch(void* const* d_in, const int* in_sizes, int n_in,
                              void* d_out, int out_size, void* d_ws, size_t ws_size,
                              hipStream_t stream) {
  const float* obs = (const float*)d_in[0];
  const float* Wih = (const float*)d_in[1];
  const float* Whh = (const float*)d_in[2];
  const float* bih = (const float*)d_in[3];
  const float* bhh = (const float*)d_in[4];
  const float* W2 = (const float*)d_in[5];
  const float* b2 = (const float*)d_in[6];
  const float* Wm = (const float*)d_in[7];
  const float* bm = (const float*)d_in[8];
  const float* Ws = (const float*)d_in[9];
  const float* bs = (const float*)d_in[10];

  char* ws = (char*)d_ws;
  h2* whh = (h2*)(ws + 0);              // 512 KB
  h2* wih_t = (h2*)(ws + 524288);       // 128 KB
  h2* w2t = (h2*)(ws + 655360);         // 128 KB
  h2* wmt = (h2*)(ws + 786432);         // 16 KB
  float* bg = (float*)(ws + 802816);    // 4 KB

  prep_kernel<<<512, 256, 0, stream>>>(Wih, Whh, bih, bhh, W2, Wm, Ws,
                                       whh, wih_t, w2t, wmt, bg);
  actor_kernel<<<NB, NTHREADS, 0, stream>>>(obs, whh, wih_t, w2t, wmt, bg, b2,
                                            bm, bs, (float*)d_out);
}

// Round 3
// 5945.215 us; speedup vs baseline: 1.4130x; 1.4130x over previous
//
#include <hip/hip_runtime.h>

// RecurrentGaussianActor: fused LSTM(64->256) + Linear+ReLU(256) + 2 heads(16).
// One WG per batch row (256 WGs x 512 threads), persistent over T=1000 steps.
//
// Round-4: back to the PROVEN register regime (512 thr, launch_bounds(512,2),
// 256 unified regs/wave -> 192 persistent weight regs with ZERO memory spill;
// rounds 2-3 proved 1024 thr/128-reg budget always spills: WRITE_SIZE 1.7GB).
// Grafted verified wins:
//  * Quad-slicing at 512 thr: thread (q=tid>>2, k=tid&3) does partial dots of
//    8 gate rows (units q, q+128 x 4 gates) over h-slice [64k,64k+64).
//    hbuf broadcast reads: 8 b128/thread/step (was 32) -> LDS return traffic
//    per CU-step 256KB -> ~130KB.
//  * DPP quad butterfly for gate exchange + double-buffered hbuf:
//    1 barrier/step (was 2), no gbuf LDS round-trip.
//  * hbuf slices padded to 144B stride (bank conflicts -81% verified).
//  * xg laid out [t][u][4g]: one b64 read per thread per step, prefetched.
//  * Transposed coalesced wih_t/w2t/wmt (verified correct in rounds 2-3).

#define NB 256
#define NT 1000
#define NF 64
#define NH 256
#define NG 1024
#define NA 16
#define NTHREADS 512
#define CHUNK 8
#define NCHUNK (NT / CHUNK)
#define HSLICE 36  // h2 units per padded h-slice (64 f16 + 8 f16 pad = 144 B)

typedef _Float16 h2 __attribute__((ext_vector_type(2)));
typedef _Float16 h4 __attribute__((ext_vector_type(4)));
typedef _Float16 h8 __attribute__((ext_vector_type(8)));
typedef float f4 __attribute__((ext_vector_type(4)));

__device__ __forceinline__ float fdot2(h2 a, h2 b, float c) {
  return __builtin_amdgcn_fdot2(a, b, c, false);
}
__device__ __forceinline__ float fexp2(float x) { return __builtin_amdgcn_exp2f(x); }
__device__ __forceinline__ float frcp(float x) { return __builtin_amdgcn_rcpf(x); }
__device__ __forceinline__ float sigmoidf_(float x) {
  return frcp(1.f + fexp2(-1.4426950408889634f * x));
}
__device__ __forceinline__ float tanhfast(float x) {
  float a = fabsf(x);
  float e = fexp2(-2.8853900817779268f * a);
  float r = (1.f - e) * frcp(1.f + e);
  return __builtin_copysignf(r, x);
}
// dot of 8 f16 elements held in two h8 vectors (4 chained v_dot2_f32_f16)
__device__ __forceinline__ float dot8(h8 x, h8 w, float acc) {
  acc = fdot2(__builtin_shufflevector(x, x, 0, 1), __builtin_shufflevector(w, w, 0, 1), acc);
  acc = fdot2(__builtin_shufflevector(x, x, 2, 3), __builtin_shufflevector(w, w, 2, 3), acc);
  acc = fdot2(__builtin_shufflevector(x, x, 4, 5), __builtin_shufflevector(w, w, 4, 5), acc);
  acc = fdot2(__builtin_shufflevector(x, x, 6, 7), __builtin_shufflevector(w, w, 6, 7), acc);
  return acc;
}
// quad_perm DPP: CTRL=0xB1 -> lanes (1,0,3,2) [xor1]; 0x4E -> (2,3,0,1) [xor2]
template <int CTRL>
__device__ __forceinline__ float qperm(float x) {
  return __int_as_float(
      __builtin_amdgcn_update_dpp(0, __float_as_int(x), CTRL, 0xF, 0xF, true));
}

// ---- prep: convert/pack weights to f16 in workspace (~790 KB) ----
// whh  : [row][128 pairs]             (feeds LDS part + wreg part)
// wih_t: [j=h8-chunk 0..8)][row]      transposed -> coalesced xg reads
// w2t  : [c=h8-chunk 0..32)][o]       transposed -> coalesced layer2 reads
// wmt  : [c=h8-chunk 0..32)][j 0..32) transposed -> coalesced head reads
__global__ void prep_kernel(const float* __restrict__ Wih, const float* __restrict__ Whh,
                            const float* __restrict__ bih, const float* __restrict__ bhh,
                            const float* __restrict__ W2, const float* __restrict__ Wm,
                            const float* __restrict__ Ws,
                            h2* __restrict__ whh, h2* __restrict__ wih_t,
                            h2* __restrict__ w2t, h2* __restrict__ wmt,
                            float* __restrict__ bg) {
  int i = blockIdx.x * 256 + threadIdx.x;
  if (i < 1024 * 128) {  // W_hh [1024][256] -> [1024][128] pairs
    int j = i >> 7, p = i & 127;
    whh[i] = h2{(_Float16)Whh[j * 256 + 2 * p], (_Float16)Whh[j * 256 + 2 * p + 1]};
  }
  if (i < 1024 * 32) {   // W_ih row r, pair p -> wih_t[(p>>2)*4096 + r*4 + (p&3)]
    int r = i >> 5, p = i & 31;
    wih_t[(p >> 2) * 4096 + r * 4 + (p & 3)] =
        h2{(_Float16)Wih[r * 64 + 2 * p], (_Float16)Wih[r * 64 + 2 * p + 1]};
  }
  if (i < 256 * 128) {   // W2 row o, pair p -> w2t[(p>>2)*1024 + o*4 + (p&3)]
    int o = i >> 7, p = i & 127;
    w2t[(p >> 2) * 1024 + o * 4 + (p & 3)] =
        h2{(_Float16)W2[o * 256 + 2 * p], (_Float16)W2[o * 256 + 2 * p + 1]};
  }
  if (i < 32 * 128) {    // Wm rows 0..15, Ws rows 16..31 -> wmt[(p>>2)*128 + j*4 + (p&3)]
    int j = i >> 7, p = i & 127;
    float v0, v1;
    if (j < 16) { v0 = Wm[j * 256 + 2 * p]; v1 = Wm[j * 256 + 2 * p + 1]; }
    else        { v0 = Ws[(j - 16) * 256 + 2 * p]; v1 = Ws[(j - 16) * 256 + 2 * p + 1]; }
    wmt[(p >> 2) * 128 + j * 4 + (p & 3)] = h2{(_Float16)v0, (_Float16)v1};
  }
  if (i < 1024) bg[i] = bih[i] + bhh[i];
}

// ---- main fused persistent kernel: 1 WG per batch row ----
__global__ __launch_bounds__(NTHREADS, 2) void actor_kernel(
    const float* __restrict__ obs,
    const h2* __restrict__ whh, const h2* __restrict__ wih_t,
    const h2* __restrict__ w2t, const h2* __restrict__ wmt,
    const float* __restrict__ bg, const float* __restrict__ b2,
    const float* __restrict__ bm, const float* __restrict__ bs,
    float* __restrict__ out) {
  // W_hh h8-slices 0..1 of this thread's 8 rows: 16 columns of [512] h8,
  // reads lane-linear b128 -> conflict-free.
  __shared__ __align__(16) h8 whh_l[16 * NTHREADS];        // 131072 B
  __shared__ __align__(16) _Float16 xg_l[CHUNK * NG];      // 16384 B  [t][u][4g]
  __shared__ __align__(16) h2 hbuf[2][4 * HSLICE];         // 1152 B padded dbuf h
  __shared__ __align__(16) h2 hch[CHUNK * NH / 2];         // 4096 B  h history
  __shared__ __align__(16) h2 xbuf[CHUNK * NF / 2];        // 1024 B  obs chunk
  __shared__ __align__(16) h2 x2b[CHUNK * NH / 2];         // 4096 B  layer2 out
  // total 157824 B <= 163840

  const int tid = threadIdx.x;
  const int b = blockIdx.x;
  const int q = tid >> 2;          // base unit of this quad (units q, q+128)
  const int k = tid & 3;           // h-slice index [64k, 64k+64)
  const int who = k >> 1;          // 0: this lane finishes unit q; 1: unit q+128
  const int u_my = q + (who << 7); // unit this lane's gate math handles

  // ---- register-resident W_hh: h8 slices 2..7 of 8 rows, slice k ----
  // 48 x h8 = 192 regs. VOLATILE: no remat-from-global inside the step loop.
  // Row order r = w*4+g  (w: unit q / q+128, g: gate i,f,g,o).
  h8 wreg[48];
  {
    const volatile h8* vw = (const volatile h8*)whh;  // row stride = 32 h8
#pragma unroll
    for (int w = 0; w < 2; w++)
#pragma unroll
      for (int g = 0; g < 4; g++)
#pragma unroll
        for (int j = 0; j < 6; j++)
          wreg[(w * 4 + g) * 6 + j] = vw[(g * 256 + q + w * 128) * 32 + k * 8 + 2 + j];
  }
  // ---- LDS-resident W_hh: h8 slices 0..1, column (r*2+s), index tid ----
  {
    const h8* whh8 = (const h8*)whh;
#pragma unroll
    for (int w = 0; w < 2; w++)
#pragma unroll
      for (int g = 0; g < 4; g++)
#pragma unroll
        for (int s = 0; s < 2; s++)
          whh_l[((w * 4 + g) * 2 + s) * NTHREADS + tid] =
              whh8[(g * 256 + q + w * 128) * 32 + k * 8 + s];
  }
  if (tid < 4 * HSLICE) hbuf[0][tid] = h2{(_Float16)0.f, (_Float16)0.f};
  float c_state = 0.f;  // lane pair (k&~1) replicates unit u_my's cell state
  const float bg0 = bg[tid], bg1 = bg[tid + 512];  // xg bias rows tid, tid+512
  const float b2v = b2[tid & 255];
  const int oh = tid & 31;
  const float hbv = (oh < NA) ? bm[oh] : bs[oh - NA];
  __syncthreads();

  const float* obs_b = obs + (size_t)b * NT * NF;
  float* out_means = out;
  float* out_stds = out + (size_t)NB * NT * NA;

  for (int ch = 0; ch < NCHUNK; ++ch) {
    const int t0 = ch * CHUNK;

    // ---- stage obs chunk -> f16 pairs in LDS ----
    if (tid < 128) {
      int t = tid >> 4, fq = tid & 15;
      f4 v = *(const f4*)(obs_b + (size_t)(t0 + t) * NF + fq * 4);
      xbuf[t * 32 + fq * 2] = h2{(_Float16)v[0], (_Float16)v[1]};
      xbuf[t * 32 + fq * 2 + 1] = h2{(_Float16)v[2], (_Float16)v[3]};
    }
    __syncthreads();

    // ---- xg for rows tid and tid+512 -> xg_l[t][u][g] (f16) ----
    // One row at a time keeps live accs at 8 (192 weight regs stay resident).
#pragma unroll
    for (int rr = 0; rr < 2; ++rr) {
      const int row = tid + rr * 512;
      const int g = row >> 8, uu = row & 255;
      float acc[CHUNK];
#pragma unroll
      for (int t = 0; t < CHUNK; t++) acc[t] = rr ? bg1 : bg0;
      const h8* wt = (const h8*)wih_t;  // [j][row], coalesced across lanes
      for (int j = 0; j < 8; j++) {
        h8 w = wt[j * 1024 + row];
#pragma unroll
        for (int t = 0; t < CHUNK; t++) {
          h8 xv = *(const h8*)&xbuf[t * 32 + j * 4];
          acc[t] = dot8(xv, w, acc[t]);
        }
      }
#pragma unroll
      for (int t = 0; t < CHUNK; t++)
        xg_l[(t * 256 + uu) * 4 + g] = (_Float16)acc[t];
    }
    __syncthreads();  // xg read cross-thread in the step loop

    // ---- 8 recurrent LSTM steps, ONE barrier each ----
    for (int t = 0; t < CHUNK; t++) {
      // padded slice: k*144B -> slice starting banks {0,4,8,12}: the 4 quad
      // addresses hit disjoint banks; same-k lanes broadcast.
      const _Float16* hb = (const _Float16*)&hbuf[t & 1][k * HSLICE];
      h4 xg4 = *(const h4*)&xg_l[(t * 256 + u_my) * 4];  // prefetch 4 gate xg
      float p[8];
#pragma unroll
      for (int i = 0; i < 8; i++) p[i] = 0.f;
#pragma unroll
      for (int s = 0; s < 2; s++) {
        h8 hv = *(const h8*)(hb + s * 8);
#pragma unroll
        for (int r = 0; r < 8; r++)
          p[r] = dot8(hv, whh_l[(r * 2 + s) * NTHREADS + tid], p[r]);
      }
#pragma unroll
      for (int j = 0; j < 6; j++) {
        h8 hv = *(const h8*)(hb + 16 + j * 8);
#pragma unroll
        for (int r = 0; r < 8; r++)
          p[r] = dot8(hv, wreg[r * 6 + j], p[r]);
      }
      // quad butterfly (DPP, VALU-only): all lanes get all 8 full sums.
#pragma unroll
      for (int i = 0; i < 8; i++) p[i] += qperm<0xB1>(p[i]);
#pragma unroll
      for (int i = 0; i < 8; i++) p[i] += qperm<0x4E>(p[i]);
      // lane pair (who) finishes ONE unit; static indexing via ternaries.
      float s0 = (who ? p[4] : p[0]) + (float)xg4[0];
      float s1 = (who ? p[5] : p[1]) + (float)xg4[1];
      float s2 = (who ? p[6] : p[2]) + (float)xg4[2];
      float s3 = (who ? p[7] : p[3]) + (float)xg4[3];
      float gi = sigmoidf_(s0);
      float gf = sigmoidf_(s1);
      float gg = tanhfast(s2);
      float go = sigmoidf_(s3);
      c_state = gf * c_state + gi * gg;
      float hval = go * tanhfast(c_state);
      if ((k & 1) == 0) {  // lanes k=0 (unit q) and k=2 (unit q+128) publish
        _Float16 hh = (_Float16)hval;
        ((_Float16*)&hbuf[(t + 1) & 1][(u_my >> 6) * HSLICE])[u_my & 63] = hh;
        ((_Float16*)hch)[t * NH + u_my] = hh;  // history for layer2
      }
      __syncthreads();  // h(t+1) visible; hbuf[t&1] free for step t+2's write
    }

    // ---- layer2: x2 = relu(h @ W2^T + b2); 512 threads x 4 timesteps ----
    {
      const int o = tid & 255;
      const int tb = (tid >> 8) * 4;
      float acc[4] = {b2v, b2v, b2v, b2v};
      const h8* wt2 = (const h8*)w2t;  // [c][o], coalesced; L2-resident re-read
      for (int c = 0; c < 32; c++) {
        h8 w = wt2[c * 256 + o];
#pragma unroll
        for (int tt = 0; tt < 4; tt++) {
          h8 xv = *(const h8*)&hch[(tb + tt) * 128 + c * 4];
          acc[tt] = dot8(xv, w, acc[tt]);
        }
      }
#pragma unroll
      for (int tt = 0; tt < 4; tt++)
        ((_Float16*)x2b)[(tb + tt) * NH + o] = (_Float16)fmaxf(acc[tt], 0.f);
    }
    __syncthreads();

    // ---- heads: 32 outputs x 8 timesteps on first 256 threads ----
    if (tid < 256) {
      const int tt = tid >> 5;
      const h8* wm8 = (const h8*)wmt;  // [c][oh], coalesced across lanes
      float acc = 0.f;
#pragma unroll 2
      for (int c = 0; c < 32; c++) {
        h8 xv = *(const h8*)&x2b[tt * 128 + c * 4];
        acc = dot8(xv, wm8[c * 32 + oh], acc);
      }
      acc += hbv;
      const size_t idx = ((size_t)b * NT + (t0 + tt)) * NA + (oh & 15);
      if (oh < NA) {
        out_means[idx] = acc;
      } else {
        float ls = fminf(fmaxf(acc, -20.f), 2.f);
        out_stds[idx] = fexp2(1.4426950408889634f * ls);
      }
    }
    // no trailing barrier: next chunk's first write to x2b (its layer2) is
    // separated from these reads by the staging/xg/step barriers.
  }
}

extern "C" void kernel_launch(void* const* d_in, const int* in_sizes, int n_in,
                              void* d_out, int out_size, void* d_ws, size_t ws_size,
                              hipStream_t stream) {
  const float* obs = (const float*)d_in[0];
  const float* Wih = (const float*)d_in[1];
  const float* Whh = (const float*)d_in[2];
  const float* bih = (const float*)d_in[3];
  const float* bhh = (const float*)d_in[4];
  const float* W2 = (const float*)d_in[5];
  const float* b2 = (const float*)d_in[6];
  const float* Wm = (const float*)d_in[7];
  const float* bm = (const float*)d_in[8];
  const float* Ws = (const float*)d_in[9];
  const float* bs = (const float*)d_in[10];

  char* ws = (char*)d_ws;
  h2* whh = (h2*)(ws + 0);              // 512 KB
  h2* wih_t = (h2*)(ws + 524288);       // 128 KB
  h2* w2t = (h2*)(ws + 655360);         // 128 KB
  h2* wmt = (h2*)(ws + 786432);         // 16 KB
  float* bg = (float*)(ws + 802816);    // 4 KB

  prep_kernel<<<512, 256, 0, stream>>>(Wih, Whh, bih, bhh, W2, Wm, Ws,
                                       whh, wih_t, w2t, wmt, bg);
  actor_kernel<<<NB, NTHREADS, 0, stream>>>(obs, whh, wih_t, w2t, wmt, bg, b2,
                                            bm, bs, (float*)d_out);
}

// Round 4
// 4554.219 us; speedup vs baseline: 1.8445x; 1.3054x over previous
//
#include <hip/hip_runtime.h>

// RecurrentGaussianActor: fused LSTM(64->256) + Linear+ReLU(256) + 2 heads(16).
// One WG per batch row (256 WGs x 512 threads), persistent over T=1000 steps.
//
// Round-5: round-0 (the ONLY no-spill configuration proven on this harness:
// FETCH 0.13 GB, 192 weight regs AGPR-resident) with EXACTLY ONE structural
// change, the step loop:
//  * 2-way half-slice: thread pair (q=tid>>1, j=tid&1) computes the 4 gate
//    rows of unit q over h-half [128j,128j+128). Per thread 16 h8 weights in
//    LDS + 48 h8 in regs -- IDENTICAL register footprint & load rhythm to
//    round 0 (1 hv read per iter, weights consumed from AGPR).
//    hbuf broadcast reads drop 32->16 b128/thread/step: LDS return traffic
//    393KB -> 266KB per CU-step on the shared LDS pipe.
//  * xor-1 DPP butterfly completes the pair's partial sums (no gbuf LDS
//    round-trip, no divergent tid<256 gate section); gate math replicated.
//  * double-buffered padded hbuf (halves at 272B stride -> disjoint banks)
//    -> ONE barrier/step (was 2).
//  * xg packed [t][u][4gates] f16: one b64 broadcast read per thread/step.
// Everything else (prep, staging, xg math, layer2, heads) is round-0 verbatim.
// Spill tell: FETCH > 1 GB means the allocator lost again.

#define NB 256
#define NT 1000
#define NF 64
#define NH 256
#define NG 1024
#define NA 16
#define NTHREADS 512
#define CHUNK 8
#define NCHUNK (NT / CHUNK)
#define HHALF 68  // h2 units per padded h-half: 128 f16 = 64 h2, +4 h2 pad = 272 B

typedef _Float16 h2 __attribute__((ext_vector_type(2)));
typedef _Float16 h4 __attribute__((ext_vector_type(4)));
typedef _Float16 h8 __attribute__((ext_vector_type(8)));
typedef float f4 __attribute__((ext_vector_type(4)));

__device__ __forceinline__ float fdot2(h2 a, h2 b, float c) {
  return __builtin_amdgcn_fdot2(a, b, c, false);
}
__device__ __forceinline__ float fexp2(float x) { return __builtin_amdgcn_exp2f(x); }
__device__ __forceinline__ float frcp(float x) { return __builtin_amdgcn_rcpf(x); }
__device__ __forceinline__ float sigmoidf_(float x) {
  return frcp(1.f + fexp2(-1.4426950408889634f * x));
}
__device__ __forceinline__ float tanhfast(float x) {
  float a = fabsf(x);
  float e = fexp2(-2.8853900817779268f * a);
  float r = (1.f - e) * frcp(1.f + e);
  return __builtin_copysignf(r, x);
}
// dot of 8 f16 elements held in two h8 vectors (4 chained v_dot2_f32_f16)
__device__ __forceinline__ float dot8(h8 x, h8 w, float acc) {
  acc = fdot2(__builtin_shufflevector(x, x, 0, 1), __builtin_shufflevector(w, w, 0, 1), acc);
  acc = fdot2(__builtin_shufflevector(x, x, 2, 3), __builtin_shufflevector(w, w, 2, 3), acc);
  acc = fdot2(__builtin_shufflevector(x, x, 4, 5), __builtin_shufflevector(w, w, 4, 5), acc);
  acc = fdot2(__builtin_shufflevector(x, x, 6, 7), __builtin_shufflevector(w, w, 6, 7), acc);
  return acc;
}
// quad_perm DPP: CTRL=0xB1 -> lanes (1,0,3,2) [xor1 within each quad]
template <int CTRL>
__device__ __forceinline__ float qperm(float x) {
  return __int_as_float(
      __builtin_amdgcn_update_dpp(0, __float_as_int(x), CTRL, 0xF, 0xF, true));
}

// ---- prep: convert/pack weights to f16 pairs in workspace (~790 KB) ----
// (round-0 verbatim)
__global__ void prep_kernel(const float* __restrict__ Wih, const float* __restrict__ Whh,
                            const float* __restrict__ bih, const float* __restrict__ bhh,
                            const float* __restrict__ W2, const float* __restrict__ Wm,
                            const float* __restrict__ Ws,
                            h2* __restrict__ whh, h2* __restrict__ wih,
                            h2* __restrict__ w2w, h2* __restrict__ wmh,
                            float* __restrict__ bg) {
  int i = blockIdx.x * 256 + threadIdx.x;
  if (i < 1024 * 128) {  // W_hh [1024][256] -> [1024][128] pairs
    int j = i >> 7, p = i & 127;
    whh[i] = h2{(_Float16)Whh[j * 256 + 2 * p], (_Float16)Whh[j * 256 + 2 * p + 1]};
  }
  if (i < 1024 * 32) {   // W_ih [1024][64] -> [1024][32] pairs
    int j = i >> 5, p = i & 31;
    wih[i] = h2{(_Float16)Wih[j * 64 + 2 * p], (_Float16)Wih[j * 64 + 2 * p + 1]};
  }
  if (i < 256 * 128) {   // W2 [256][256] -> [256][128] pairs
    int j = i >> 7, p = i & 127;
    w2w[i] = h2{(_Float16)W2[j * 256 + 2 * p], (_Float16)W2[j * 256 + 2 * p + 1]};
  }
  if (i < 32 * 128) {    // Wm rows 0..15, Ws rows 16..31
    int j = i >> 7, p = i & 127;
    float v0, v1;
    if (j < 16) { v0 = Wm[j * 256 + 2 * p]; v1 = Wm[j * 256 + 2 * p + 1]; }
    else        { v0 = Ws[(j - 16) * 256 + 2 * p]; v1 = Ws[(j - 16) * 256 + 2 * p + 1]; }
    wmh[i] = h2{(_Float16)v0, (_Float16)v1};
  }
  if (i < 1024) bg[i] = bih[i] + bhh[i];
}

// ---- main fused persistent kernel: 1 WG per batch row ----
__global__ __launch_bounds__(NTHREADS, 2) void actor_kernel(
    const float* __restrict__ obs,
    const h2* __restrict__ whh, const h2* __restrict__ wih,
    const h2* __restrict__ w2w, const h2* __restrict__ wmh,
    const float* __restrict__ bg, const float* __restrict__ b2,
    const float* __restrict__ bm, const float* __restrict__ bs,
    float* __restrict__ out) {
  // W_hh h8-slices 0..3 of this thread's (4 rows x own h-half): 16 columns
  // of [512] h8; reads lane-linear b128 -> conflict-free (round-0 pattern).
  __shared__ __align__(16) h8 whh_l[16 * NTHREADS];        // 131072 B
  __shared__ __align__(16) _Float16 xg_l[CHUNK * NG];      // 16384 B [t][u][4g]
  __shared__ __align__(16) h2 hbuf[2][2 * HHALF];          // 1088 B padded dbuf h
  __shared__ __align__(16) h2 hch[CHUNK * NH / 2];         // 4096 B  h history
  __shared__ __align__(16) h2 xbuf[CHUNK * NF / 2];        // 1024 B  obs chunk
  __shared__ __align__(16) h2 x2b[CHUNK * NH / 2];         // 4096 B  layer2 out
  // total 157760 B <= 163840

  const int tid = threadIdx.x;
  const int b = blockIdx.x;
  const int q = tid >> 1;      // hidden unit owned by this lane pair
  const int jhalf = tid & 1;   // h-half [128*jhalf, 128*jhalf+128)

  // ---- register-resident W_hh: h8s 4..15 of own half, 4 gate rows of q ----
  // 48 x h8 = 192 regs (round-0 footprint). VOLATILE: no remat-from-global
  // inside the step loop.
  h8 wreg[48];
  {
    const volatile h8* vw = (const volatile h8*)whh;  // row stride = 32 h8
#pragma unroll
    for (int g = 0; g < 4; g++)
#pragma unroll
      for (int jj = 0; jj < 12; jj++)
        wreg[g * 12 + jj] = vw[(g * 256 + q) * 32 + jhalf * 16 + 4 + jj];
  }
  // ---- LDS-resident W_hh: h8s 0..3 of own half, column (g*4+s), idx tid ----
  {
    const h8* whh8 = (const h8*)whh;
#pragma unroll
    for (int g = 0; g < 4; g++)
#pragma unroll
      for (int s = 0; s < 4; s++)
        whh_l[(g * 4 + s) * NTHREADS + tid] = whh8[(g * 256 + q) * 32 + jhalf * 16 + s];
  }
  if (tid < 2 * HHALF) hbuf[0][tid] = h2{(_Float16)0.f, (_Float16)0.f};
  float c_state = 0.f;  // replicated across the lane pair
  const float bg0 = bg[tid], bg1 = bg[tid + 512];  // xg bias rows tid, tid+512
  const float b2v = b2[tid & 255];
  const int oh = tid & 31;
  const float hbv = (oh < NA) ? bm[oh] : bs[oh - NA];
  __syncthreads();

  const float* obs_b = obs + (size_t)b * NT * NF;
  float* out_means = out;
  float* out_stds = out + (size_t)NB * NT * NA;

  for (int ch = 0; ch < NCHUNK; ++ch) {
    const int t0 = ch * CHUNK;

    // ---- stage obs chunk -> f16 pairs in LDS (round-0 verbatim) ----
    if (tid < 128) {
      int t = tid >> 4, fq = tid & 15;
      f4 v = *(const f4*)(obs_b + (size_t)(t0 + t) * NF + fq * 4);
      xbuf[t * 32 + fq * 2] = h2{(_Float16)v[0], (_Float16)v[1]};
      xbuf[t * 32 + fq * 2 + 1] = h2{(_Float16)v[2], (_Float16)v[3]};
    }
    __syncthreads();

    // ---- xg for rows tid and tid+512 (round-0 math, [t][u][4g] store) ----
#pragma unroll
    for (int rr = 0; rr < 2; ++rr) {
      const int row = tid + rr * 512;
      const float bias = rr ? bg1 : bg0;
      float acc[CHUNK];
#pragma unroll
      for (int t = 0; t < CHUNK; t++) acc[t] = bias;
      const h8* wrow = (const h8*)wih + row * 8;
#pragma unroll
      for (int jh = 0; jh < 2; jh++) {
        h8 w[4];
#pragma unroll
        for (int qq = 0; qq < 4; qq++) w[qq] = wrow[jh * 4 + qq];
#pragma unroll
        for (int t = 0; t < CHUNK; t++) {
#pragma unroll
          for (int qq = 0; qq < 4; qq++) {
            h8 xv = *(const h8*)&xbuf[t * 32 + jh * 16 + qq * 4];
            acc[t] = dot8(xv, w[qq], acc[t]);
          }
        }
      }
      const int g = row >> 8, uu = row & 255;
#pragma unroll
      for (int t = 0; t < CHUNK; t++)
        xg_l[(t * 256 + uu) * 4 + g] = (_Float16)acc[t];
    }
    __syncthreads();

    // ---- 8 recurrent LSTM steps, ONE barrier each ----
    for (int t = 0; t < CHUNK; t++) {
      // halves at 272B stride: even lanes bank 0.., odd lanes bank 4.. ->
      // two disjoint broadcast groups, conflict-free.
      const _Float16* hb = (const _Float16*)&hbuf[t & 1][jhalf * HHALF];
      h4 xg4 = *(const h4*)&xg_l[(t * 256 + q) * 4];  // b64 broadcast
      float p0 = 0.f, p1 = 0.f, p2 = 0.f, p3 = 0.f;
#pragma unroll
      for (int s = 0; s < 4; s++) {
        h8 hv = *(const h8*)(hb + s * 8);
        p0 = dot8(hv, whh_l[(0 * 4 + s) * NTHREADS + tid], p0);
        p1 = dot8(hv, whh_l[(1 * 4 + s) * NTHREADS + tid], p1);
        p2 = dot8(hv, whh_l[(2 * 4 + s) * NTHREADS + tid], p2);
        p3 = dot8(hv, whh_l[(3 * 4 + s) * NTHREADS + tid], p3);
      }
#pragma unroll
      for (int jj = 0; jj < 12; jj++) {
        h8 hv = *(const h8*)(hb + 32 + jj * 8);
        p0 = dot8(hv, wreg[jj], p0);
        p1 = dot8(hv, wreg[12 + jj], p1);
        p2 = dot8(hv, wreg[24 + jj], p2);
        p3 = dot8(hv, wreg[36 + jj], p3);
      }
      // xor-1 DPP butterfly: both lanes of the pair get all 4 full sums.
      p0 += qperm<0xB1>(p0);
      p1 += qperm<0xB1>(p1);
      p2 += qperm<0xB1>(p2);
      p3 += qperm<0xB1>(p3);
      float gi = sigmoidf_(p0 + (float)xg4[0]);
      float gf = sigmoidf_(p1 + (float)xg4[1]);
      float gg = tanhfast(p2 + (float)xg4[2]);
      float go = sigmoidf_(p3 + (float)xg4[3]);
      c_state = gf * c_state + gi * gg;
      float hval = go * tanhfast(c_state);
      if (jhalf == 0) {  // one lane per unit publishes
        _Float16 hh = (_Float16)hval;
        ((_Float16*)&hbuf[(t + 1) & 1][(q >> 7) * HHALF])[q & 127] = hh;
        ((_Float16*)hch)[t * NH + q] = hh;  // history for layer2
      }
      __syncthreads();  // h(t+1) visible; hbuf[t&1] free for step t+2's write
    }

    // ---- layer2: x2 = relu(h @ W2^T + b2) (round-0 verbatim) ----
    {
      const int o = tid & 255;
      const int tb = (tid >> 8) * 4;  // 4 timesteps per thread
      float acc[4] = {b2v, b2v, b2v, b2v};
      const h8* wrow = (const h8*)w2w + o * 32;
#pragma unroll 2
      for (int c = 0; c < 8; c++) {
        h8 w[4];
#pragma unroll
        for (int qq = 0; qq < 4; qq++) w[qq] = wrow[c * 4 + qq];
#pragma unroll
        for (int tt = 0; tt < 4; tt++) {
#pragma unroll
          for (int qq = 0; qq < 4; qq++) {
            h8 xv = *(const h8*)&hch[(tb + tt) * 128 + c * 16 + qq * 4];
            acc[tt] = dot8(xv, w[qq], acc[tt]);
          }
        }
      }
#pragma unroll
      for (int tt = 0; tt < 4; tt++)
        ((_Float16*)x2b)[(tb + tt) * NH + o] = (_Float16)fmaxf(acc[tt], 0.f);
    }
    __syncthreads();

    // ---- heads: 32 outputs x 8 timesteps on first 256 threads (verbatim) ----
    if (tid < 256) {
      const int tt = tid >> 5;
      const h8* wrow = (const h8*)wmh + oh * 32;
      float acc = 0.f;
#pragma unroll 4
      for (int c = 0; c < 32; c++) {
        h8 xv = *(const h8*)&x2b[tt * 128 + c * 4];
        acc = dot8(xv, wrow[c], acc);
      }
      acc += hbv;
      const size_t idx = ((size_t)b * NT + (t0 + tt)) * NA + (oh & 15);
      if (oh < NA) {
        out_means[idx] = acc;
      } else {
        float ls = fminf(fmaxf(acc, -20.f), 2.f);
        out_stds[idx] = fexp2(1.4426950408889634f * ls);
      }
    }
    // no trailing barrier: next chunk's first write to x2b (its layer2) is
    // separated from these reads by the staging/xg/step barriers.
  }
}

extern "C" void kernel_launch(void* const* d_in, const int* in_sizes, int n_in,
                              void* d_out, int out_size, void* d_ws, size_t ws_size,
                              hipStream_t stream) {
  const float* obs = (const float*)d_in[0];
  const float* Wih = (const float*)d_in[1];
  const float* Whh = (const float*)d_in[2];
  const float* bih = (const float*)d_in[3];
  const float* bhh = (const float*)d_in[4];
  const float* W2 = (const float*)d_in[5];
  const float* b2 = (const float*)d_in[6];
  const float* Wm = (const float*)d_in[7];
  const float* bm = (const float*)d_in[8];
  const float* Ws = (const float*)d_in[9];
  const float* bs = (const float*)d_in[10];

  char* ws = (char*)d_ws;
  h2* whh = (h2*)(ws + 0);            // 512 KB
  h2* wih = (h2*)(ws + 524288);       // 128 KB
  h2* w2w = (h2*)(ws + 655360);       // 128 KB
  h2* wmh = (h2*)(ws + 786432);       // 16 KB
  float* bg = (float*)(ws + 802816);  // 4 KB

  prep_kernel<<<512, 256, 0, stream>>>(Wih, Whh, bih, bhh, W2, Wm, Ws,
                                       whh, wih, w2w, wmh, bg);
  actor_kernel<<<NB, NTHREADS, 0, stream>>>(obs, whh, wih, w2w, wmh, bg, b2, bm,
                                            bs, (float*)d_out);
}